// Round 5
// baseline (82.413 us; speedup 1.0000x reference)
//
#include <hip/hip_runtime.h>
#include <math.h>

// CapsShapeLayer: B=256, D=10, M=32, P=36, I=8, O=16, 3 routing iters
// R17 = R16 + dependency-chain shortening (latency-bound at 2.5 waves/SIMD):
//  (1) s1/s2/s3: 2 accumulators over j + tree-shaped dot8 -> FMA chain
//      depth ~64 -> ~16.
//  (2) v_l LDS roundtrips deleted: after the xor-reduce every lane holds
//      v[its o], so z1's vs[16] and z2's vsel[8] come from __shfl lane
//      broadcasts (no exec-masked write, no lgkmcnt(0) wait, no b128
//      re-reads). v_l buffer removed.
//  (3) softmax-d / final-softmax denominator chains split into 2 accs.
// Skeleton: 1 block/batch, 10 waves, wave owns d, 3 barriers.
// Wave caches its W[d] s-slice in 64 VGPRs; log2(e) folded into stored z;
// padded-stride xs (XS=292, bank-balanced b128, compile-time DS offsets);
// normalized probs cds computed once in softmax-d, reused by y2.
#define BB 256
#define DD 10
#define MM 32
#define PP 36
#define PH2 18
#define II 8
#define OO 16
#define NT 640        // 10 waves = one per d
#define XS 292        // xs row stride (pad 4: 16B-aligned, bank-balanced b128)
#define RS 37         // c row stride: gcd(5,32)=1 -> conflict-free over m
#define LOG2E 1.44269504088896f
#define EXP2(v) __builtin_amdgcn_exp2f(v)
#define RCP(v)  __builtin_amdgcn_rcpf(v)

__device__ __forceinline__ float dot8(const float4 a0, const float4 a1,
                                      const float4 b0, const float4 b1) {
    // tree shape: depth ~3 fma instead of 8-deep chain
    const float t0 = a0.x*b0.x + a0.y*b0.y;
    const float t1 = a0.z*b0.z + a0.w*b0.w;
    const float t2 = a1.x*b1.x + a1.y*b1.y;
    const float t3 = a1.z*b1.z + a1.w*b1.w;
    return (t0 + t1) + (t2 + t3);
}

__global__ void __launch_bounds__(NT, 3) caps_routing(
    const float* __restrict__ x,   // (B, M, P, I)
    const float* __restrict__ W,   // (D, M, O, I)
    float* __restrict__ out)       // (B, D, O)
{
    const int bidx = blockIdx.x;
    const int tid  = threadIdx.x;
    const int wave = tid >> 6;          // d owned by this wave (0..9)
    const int lane = tid & 63;
    const float* __restrict__ xb = x + (size_t)bidx * (MM*PP*II);

    __shared__ __align__(16) float xs  [MM*XS];     // 37376 B  x staged once (padded)
    __shared__ __align__(16) float z   [DD*MM*II];  // 10240 B  K*z1 (softmax-d needs all d)
    __shared__ __align__(16) float y   [DD*MM*II];  // 10240 B  per-wave y scratch
    __shared__ __align__(16) float ybar[MM*II];     //  1024 B
    __shared__ __align__(16) float cds [DD*MM*RS];  // 47360 B  normalized c2[d][m][p]
    // total 106240 B (1 block/CU regardless; 160 KiB available)

    const int d  = wave;
    const int o  = lane & 15, qq = lane >> 4;       // s-stage laning: (o, m-quarter)

    // ---- cache this wave's W[d] s-slice in regs: 8 rows (m=qq*8+j) x 32B ----
    float4 wr0[8], wr1[8];
    #pragma unroll
    for (int j = 0; j < 8; ++j) {
        const float4* wp = (const float4*)(W + ((size_t)((d*MM + qq*8 + j)*OO + o)) * II);
        wr0[j] = wp[0]; wr1[j] = wp[1];
    }

    // ======== stage 0: x -> LDS (padded rows) + ybar from global ========
    {
        const float4* xg = (const float4*)xb;
        #pragma unroll
        for (int k = 0; k < 4; ++k) {                 // 2304 float4 over 640 thr
            const int t = tid + k*NT;                 // tid>=384 does only 3 iters
            if (t < MM*72) {
                const int m = t / 72, c = t - m*72;
                *(float4*)(xs + m*XS + 4*c) = xg[t];
            }
        }
        if (tid >= NT - MM*II) {                      // ybar on threads 384..639
            const int m = (tid - (NT - MM*II)) >> 3, i = tid & 7;
            const float* xr = xb + m*(PP*II) + i;
            float a0 = 0.f, a1 = 0.f, a2 = 0.f, a3 = 0.f;
            #pragma unroll
            for (int p = 0; p < PP; p += 4) {         // all 36 loads in flight
                a0 += xr[(p    )*II];
                a1 += xr[(p + 1)*II];
                a2 += xr[(p + 2)*II];
                a3 += xr[(p + 3)*II];
            }
            ybar[m*II + i] = 0.1f * ((a0 + a1) + (a2 + a3));
        }
    }
    __syncthreads();                                  // BARRIER 1

    // ======== per-wave: s1 (regs) -> v1 -> K*z1 -> LDS ========
    {
        float s1a = 0.f, s1b = 0.f;
        #pragma unroll
        for (int j = 0; j < 8; j += 2) {
            const float4* ya = (const float4*)(ybar + (qq*8 + j)*II);
            const float4* yb = (const float4*)(ybar + (qq*8 + j + 1)*II);
            s1a += dot8(wr0[j],   wr1[j],   ya[0], ya[1]);
            s1b += dot8(wr0[j+1], wr1[j+1], yb[0], yb[1]);
        }
        float s1 = s1a + s1b;
        s1 += __shfl_xor(s1, 16, 64);
        s1 += __shfl_xor(s1, 32, 64);
        float sq = s1 * s1;
        sq += __shfl_xor(sq, 1, 64);
        sq += __shfl_xor(sq, 2, 64);
        sq += __shfl_xor(sq, 4, 64);
        sq += __shfl_xor(sq, 8, 64);
        const float v1 = (sq / (1.f + sq)) * (s1 / sqrtf(sq + 1e-7f));
        // every lane holds v1[its o]; broadcast all 16 via shfl (no LDS)
        float vs[16];
        #pragma unroll
        for (int o2 = 0; o2 < OO; ++o2) vs[o2] = __shfl(v1, o2, 64);

        // z1: lane = (m, i-half); W b128 over o; store K*z1 for exp2
        const int mz = lane >> 1, ihz = lane & 1;
        const float* wz = W + ((size_t)(d*MM + mz)*OO) * II + ihz*4;
        float a0 = 0.f, a1 = 0.f, a2 = 0.f, a3 = 0.f;
        float b0 = 0.f, b1 = 0.f, b2 = 0.f, b3 = 0.f;
        #pragma unroll
        for (int o2 = 0; o2 < OO; o2 += 2) {
            const float4 wv = *(const float4*)(wz + o2*II);
            const float4 wu = *(const float4*)(wz + (o2+1)*II);
            a0 += wv.x * vs[o2];   a1 += wv.y * vs[o2];
            a2 += wv.z * vs[o2];   a3 += wv.w * vs[o2];
            b0 += wu.x * vs[o2+1]; b1 += wu.y * vs[o2+1];
            b2 += wu.z * vs[o2+1]; b3 += wu.w * vs[o2+1];
        }
        *(float4*)(z + (d*MM + mz)*II + ihz*4) =
            make_float4((a0+b0)*LOG2E, (a1+b1)*LOG2E,
                        (a2+b2)*LOG2E, (a3+b3)*LOG2E);
    }
    __syncthreads();                                  // BARRIER 2

    // ======== softmax over d: cds[d][m][p] = e_d / sum_d e_d ========
    // (|b| small -> no max subtraction; e computed ONCE, reused by y2)
    // 576 threads own (m,q), process p=q and p=q+18: z rows read once
    // (18-lane same-m groups broadcast), single pass.
    if (tid < MM*PH2) {
        const int m = tid / PH2, q = tid - m*PH2;
        const float* xr = xs + m*XS;
        const float4 xa0 = *(const float4*)(xr + 8*q);
        const float4 xa1 = *(const float4*)(xr + 8*q + 4);
        const float4 xb0 = *(const float4*)(xr + 8*q + 8*PH2);
        const float4 xb1 = *(const float4*)(xr + 8*q + 8*PH2 + 4);
        float eA[DD], eB[DD];
        float seA0 = 0.f, seA1 = 0.f, seB0 = 0.f, seB1 = 0.f;
        #pragma unroll
        for (int d2 = 0; d2 < DD; d2 += 2) {
            const float4* zp0 = (const float4*)(z + (d2*MM + m)*II);
            const float4* zp1 = (const float4*)(z + ((d2+1)*MM + m)*II);
            eA[d2]   = EXP2(dot8(xa0, xa1, zp0[0], zp0[1])); seA0 += eA[d2];
            eB[d2]   = EXP2(dot8(xb0, xb1, zp0[0], zp0[1])); seB0 += eB[d2];
            eA[d2+1] = EXP2(dot8(xa0, xa1, zp1[0], zp1[1])); seA1 += eA[d2+1];
            eB[d2+1] = EXP2(dot8(xb0, xb1, zp1[0], zp1[1])); seB1 += eB[d2+1];
        }
        const float rA = RCP(seA0 + seA1);
        const float rB = RCP(seB0 + seB1);
        #pragma unroll
        for (int d2 = 0; d2 < DD; ++d2) {
            float* cp = cds + (d2*MM + m)*RS;
            cp[q]       = eA[d2] * rA;
            cp[q + PH2] = eB[d2] * rB;
        }
    }
    __syncthreads();                                  // BARRIER 3 (last)

    // ======== tail: y2 -> s2(regs) -> v2 -> z2(regs) -> final -> s3(regs) -> out ========
    {
        const float* __restrict__ zd = z + d*(MM*II);
        float* __restrict__ yd = y + d*(MM*II);

        const int mF = lane & 31;                     // m owned by this lane
        const int ph = lane >> 5;                     // p-half (0/1), partner = lane^32
        const float* xrow = xs + mF*XS + ph*(8*PH2);  // all reads: base + imm offset
        const float4 zf0 = *(const float4*)(zd + mF*II);       // K*z1 halves
        const float4 zf1 = *(const float4*)(zd + mF*II + 4);

        // ---- y2: 18 iters, precomputed probs from cds (no dot8/exp2) ----
        {
            const float* cp = cds + (d*MM + mF)*RS + ph*PH2;
            float a0=0.f,a1=0.f,a2=0.f,a3=0.f,a4=0.f,a5=0.f,a6=0.f,a7=0.f;
            #pragma unroll 6
            for (int q = 0; q < PH2; ++q) {
                const float4 x0 = *(const float4*)(xrow + 8*q);
                const float4 x1 = *(const float4*)(xrow + 8*q + 4);
                const float e = cp[q];
                a0 += e*x0.x; a1 += e*x0.y; a2 += e*x0.z; a3 += e*x0.w;
                a4 += e*x1.x; a5 += e*x1.y; a6 += e*x1.z; a7 += e*x1.w;
            }
            a0 += __shfl_xor(a0, 32, 64); a1 += __shfl_xor(a1, 32, 64);
            a2 += __shfl_xor(a2, 32, 64); a3 += __shfl_xor(a3, 32, 64);
            a4 += __shfl_xor(a4, 32, 64); a5 += __shfl_xor(a5, 32, 64);
            a6 += __shfl_xor(a6, 32, 64); a7 += __shfl_xor(a7, 32, 64);
            const float4 wv = ph ? make_float4(a4,a5,a6,a7) : make_float4(a0,a1,a2,a3);
            *(float4*)(yd + mF*II + ph*4) = wv;
        }
        // in-wave LDS write->read ordering via lgkmcnt; no barrier

        // ---- s2 (from regs) -> v2 ----
        float s2a = 0.f, s2b = 0.f;
        #pragma unroll
        for (int j = 0; j < 8; j += 2) {
            const float4* ya = (const float4*)(yd + (qq*8 + j)*II);
            const float4* yb = (const float4*)(yd + (qq*8 + j + 1)*II);
            s2a += dot8(wr0[j],   wr1[j],   ya[0], ya[1]);
            s2b += dot8(wr0[j+1], wr1[j+1], yb[0], yb[1]);
        }
        float s2 = s2a + s2b;
        s2 += __shfl_xor(s2, 16, 64);
        s2 += __shfl_xor(s2, 32, 64);
        float sq = s2 * s2;
        sq += __shfl_xor(sq, 1, 64);
        sq += __shfl_xor(sq, 2, 64);
        sq += __shfl_xor(sq, 4, 64);
        sq += __shfl_xor(sq, 8, 64);
        const float v2 = (sq / (1.f + sq)) * (s2 / sqrtf(sq + 1e-7f));
        // every lane holds v2[its o]; z2 needs only its o-half -> 8 shfls
        float vsel[8];
        #pragma unroll
        for (int j = 0; j < 8; ++j) vsel[j] = __shfl(v2, ph*8 + j, 64);

        // ---- z2: lane (mF, ph) does its o-half (global W), xor(32) combine ----
        float4 zf20, zf21;
        {
            const float* wz = W + ((size_t)(d*MM + mF)*OO) * II;
            float b0=0.f,b1=0.f,b2=0.f,b3=0.f,b4=0.f,b5=0.f,b6=0.f,b7=0.f;
            #pragma unroll
            for (int j = 0; j < 8; ++j) {
                const int o2 = ph*8 + j;
                const float4 w0 = *(const float4*)(wz + o2*II);
                const float4 w1 = *(const float4*)(wz + o2*II + 4);
                const float sv = vsel[j];
                b0 += w0.x*sv; b1 += w0.y*sv; b2 += w0.z*sv; b3 += w0.w*sv;
                b4 += w1.x*sv; b5 += w1.y*sv; b6 += w1.z*sv; b7 += w1.w*sv;
            }
            b0 += __shfl_xor(b0, 32, 64); b1 += __shfl_xor(b1, 32, 64);
            b2 += __shfl_xor(b2, 32, 64); b3 += __shfl_xor(b3, 32, 64);
            b4 += __shfl_xor(b4, 32, 64); b5 += __shfl_xor(b5, 32, 64);
            b6 += __shfl_xor(b6, 32, 64); b7 += __shfl_xor(b7, 32, 64);
            zf20 = make_float4(zf0.x + b0*LOG2E, zf0.y + b1*LOG2E,
                               zf0.z + b2*LOG2E, zf0.w + b3*LOG2E);
            zf21 = make_float4(zf1.x + b4*LOG2E, zf1.y + b5*LOG2E,
                               zf1.z + b6*LOG2E, zf1.w + b7*LOG2E);
        }

        // ---- final softmax over P: single pass, exp2 ----
        {
            float se0 = 0.f, se1 = 0.f;
            float a0=0.f,a1=0.f,a2=0.f,a3=0.f,a4=0.f,a5=0.f,a6=0.f,a7=0.f;
            #pragma unroll 6
            for (int q = 0; q < PH2; ++q) {
                const float4 x0 = *(const float4*)(xrow + 8*q);
                const float4 x1 = *(const float4*)(xrow + 8*q + 4);
                const float e = EXP2(dot8(x0, x1, zf20, zf21));
                if (q & 1) se1 += e; else se0 += e;
                a0 += e*x0.x; a1 += e*x0.y; a2 += e*x0.z; a3 += e*x0.w;
                a4 += e*x1.x; a5 += e*x1.y; a6 += e*x1.z; a7 += e*x1.w;
            }
            float se = se0 + se1;
            se += __shfl_xor(se, 32, 64);
            a0 += __shfl_xor(a0, 32, 64); a1 += __shfl_xor(a1, 32, 64);
            a2 += __shfl_xor(a2, 32, 64); a3 += __shfl_xor(a3, 32, 64);
            a4 += __shfl_xor(a4, 32, 64); a5 += __shfl_xor(a5, 32, 64);
            a6 += __shfl_xor(a6, 32, 64); a7 += __shfl_xor(a7, 32, 64);
            const float rs = RCP(se);
            const float4 wv = ph ? make_float4(a4*rs,a5*rs,a6*rs,a7*rs)
                                 : make_float4(a0*rs,a1*rs,a2*rs,a3*rs);
            *(float4*)(yd + mF*II + ph*4) = wv;
        }

        // ---- s3 (from regs) -> squash -> out ----
        float s3a = 0.f, s3b = 0.f;
        #pragma unroll
        for (int j = 0; j < 8; j += 2) {
            const float4* ya = (const float4*)(yd + (qq*8 + j)*II);
            const float4* yb = (const float4*)(yd + (qq*8 + j + 1)*II);
            s3a += dot8(wr0[j],   wr1[j],   ya[0], ya[1]);
            s3b += dot8(wr0[j+1], wr1[j+1], yb[0], yb[1]);
        }
        float s3 = s3a + s3b;
        s3 += __shfl_xor(s3, 16, 64);
        s3 += __shfl_xor(s3, 32, 64);
        float sq3 = s3 * s3;
        sq3 += __shfl_xor(sq3, 1, 64);
        sq3 += __shfl_xor(sq3, 2, 64);
        sq3 += __shfl_xor(sq3, 4, 64);
        sq3 += __shfl_xor(sq3, 8, 64);
        const float r = (sq3 / (1.f + sq3)) * (s3 / sqrtf(sq3 + 1e-7f));
        if (lane < OO)
            out[(size_t)bidx * (DD*OO) + d*OO + o] = r;
    }
}

extern "C" void kernel_launch(void* const* d_in, const int* in_sizes, int n_in,
                              void* d_out, int out_size, void* d_ws, size_t ws_size,
                              hipStream_t stream) {
    (void)in_sizes; (void)n_in; (void)out_size; (void)d_ws; (void)ws_size;
    const float* x = (const float*)d_in[0];  // (B, M, P, I)
    const float* W = (const float*)d_in[1];  // (1, D, M, 1, O, I)
    float* out = (float*)d_out;              // (B, D, O)
    caps_routing<<<dim3(BB), dim3(NT), 0, stream>>>(x, W, out);
}

// Round 6
// 81.155 us; speedup vs baseline: 1.0155x; 1.0155x over previous
//
#include <hip/hip_runtime.h>
#include <math.h>

// CapsShapeLayer: B=256, D=10, M=32, P=36, I=8, O=16, 3 routing iters
// R18 = R16 (full revert of R17's shfl-broadcast/tree-dot8 regression,
// mechanism: __shfl = ds_bpermute on CDNA -> 24 serial LDS-pipe ops beat
// the single v_l roundtrip they replaced) + W-slice register prefetch:
//  (1) z1's 16 float4 W loads issued at kernel start (hidden under
//      stage-0 staging) instead of after BARRIER 1 on the B1->B2 path.
//  (2) z2's 16 float4 W loads issued right after BARRIER 2 (hidden under
//      softmax-d) instead of in the serial tail after BARRIER 3.
// W loads are pure inputs, L2-hot; each removal hides one ~250-cyc L2
// latency window from a serial phase. +64 VGPR transient, no spill risk
// (LDS-bound occupancy, cap 682).
// Skeleton: 1 block/batch, 10 waves, wave owns d, 3 barriers.
// Wave caches its W[d] s-slice in 64 VGPRs; log2(e) folded into stored z;
// padded-stride xs (XS=292, bank-balanced b128, compile-time DS offsets);
// normalized probs cds computed once in softmax-d, reused by y2.
#define BB 256
#define DD 10
#define MM 32
#define PP 36
#define PH2 18
#define II 8
#define OO 16
#define NT 640        // 10 waves = one per d
#define XS 292        // xs row stride (pad 4: 16B-aligned, bank-balanced b128)
#define RS 37         // c row stride: gcd(5,32)=1 -> conflict-free over m
#define LOG2E 1.44269504088896f
#define EXP2(v) __builtin_amdgcn_exp2f(v)
#define RCP(v)  __builtin_amdgcn_rcpf(v)

__device__ __forceinline__ float dot8(const float4 a0, const float4 a1,
                                      const float4 b0, const float4 b1) {
    return a0.x*b0.x + a0.y*b0.y + a0.z*b0.z + a0.w*b0.w
         + a1.x*b1.x + a1.y*b1.y + a1.z*b1.z + a1.w*b1.w;
}

__global__ void __launch_bounds__(NT, 3) caps_routing(
    const float* __restrict__ x,   // (B, M, P, I)
    const float* __restrict__ W,   // (D, M, O, I)
    float* __restrict__ out)       // (B, D, O)
{
    const int bidx = blockIdx.x;
    const int tid  = threadIdx.x;
    const int wave = tid >> 6;          // d owned by this wave (0..9)
    const int lane = tid & 63;
    const float* __restrict__ xb = x + (size_t)bidx * (MM*PP*II);

    __shared__ __align__(16) float xs  [MM*XS];     // 37376 B  x staged once (padded)
    __shared__ __align__(16) float z   [DD*MM*II];  // 10240 B  K*z1 (softmax-d needs all d)
    __shared__ __align__(16) float y   [DD*MM*II];  // 10240 B  per-wave y scratch
    __shared__ __align__(16) float ybar[MM*II];     //  1024 B
    __shared__ __align__(16) float cds [DD*MM*RS];  // 47360 B  normalized c2[d][m][p]
    __shared__ __align__(16) float v_l [DD*OO];     //   640 B
    // total 106880 B (1 block/CU regardless; 160 KiB available)

    const int d  = wave;
    const int o  = lane & 15, qq = lane >> 4;       // s-stage laning: (o, m-quarter)

    // ---- cache this wave's W[d] s-slice in regs: 8 rows (m=qq*8+j) x 32B ----
    float4 wr0[8], wr1[8];
    #pragma unroll
    for (int j = 0; j < 8; ++j) {
        const float4* wp = (const float4*)(W + ((size_t)((d*MM + qq*8 + j)*OO + o)) * II);
        wr0[j] = wp[0]; wr1[j] = wp[1];
    }

    // ---- prefetch z1's W slice NOW (consumed after BARRIER 1; loads
    //      overlap stage-0 staging instead of sitting on the B1->B2 path) ----
    const int mz = lane >> 1, ihz = lane & 1;
    float4 wzr[16];
    {
        const float* wzp = W + ((size_t)(d*MM + mz)*OO) * II + ihz*4;
        #pragma unroll
        for (int o2 = 0; o2 < OO; ++o2)
            wzr[o2] = *(const float4*)(wzp + o2*II);
    }

    // ======== stage 0: x -> LDS (padded rows) + ybar from global ========
    {
        const float4* xg = (const float4*)xb;
        #pragma unroll
        for (int k = 0; k < 4; ++k) {                 // 2304 float4 over 640 thr
            const int t = tid + k*NT;                 // tid>=384 does only 3 iters
            if (t < MM*72) {
                const int m = t / 72, c = t - m*72;
                *(float4*)(xs + m*XS + 4*c) = xg[t];
            }
        }
        if (tid >= NT - MM*II) {                      // ybar on threads 384..639
            const int m = (tid - (NT - MM*II)) >> 3, i = tid & 7;
            const float* xr = xb + m*(PP*II) + i;
            float a0 = 0.f, a1 = 0.f, a2 = 0.f, a3 = 0.f;
            #pragma unroll
            for (int p = 0; p < PP; p += 4) {         // all 36 loads in flight
                a0 += xr[(p    )*II];
                a1 += xr[(p + 1)*II];
                a2 += xr[(p + 2)*II];
                a3 += xr[(p + 3)*II];
            }
            ybar[m*II + i] = 0.1f * ((a0 + a1) + (a2 + a3));
        }
    }
    __syncthreads();                                  // BARRIER 1

    // ======== per-wave: s1 (regs) -> v1 -> K*z1 -> LDS ========
    {
        float s1 = 0.f;
        #pragma unroll
        for (int j = 0; j < 8; ++j) {
            const float4* yp = (const float4*)(ybar + (qq*8 + j)*II);
            s1 += dot8(wr0[j], wr1[j], yp[0], yp[1]);
        }
        s1 += __shfl_xor(s1, 16, 64);
        s1 += __shfl_xor(s1, 32, 64);
        float sq = s1 * s1;
        sq += __shfl_xor(sq, 1, 64);
        sq += __shfl_xor(sq, 2, 64);
        sq += __shfl_xor(sq, 4, 64);
        sq += __shfl_xor(sq, 8, 64);
        const float v1 = (sq / (1.f + sq)) * (s1 / sqrtf(sq + 1e-7f));
        if (lane < OO) v_l[d*OO + lane] = v1;

        // z1: lane = (m, i-half); W from prefetched regs; store K*z1
        const float4 vv0 = *(const float4*)(v_l + d*OO);
        const float4 vv1 = *(const float4*)(v_l + d*OO + 4);
        const float4 vv2 = *(const float4*)(v_l + d*OO + 8);
        const float4 vv3 = *(const float4*)(v_l + d*OO + 12);
        const float vs[16] = {vv0.x,vv0.y,vv0.z,vv0.w, vv1.x,vv1.y,vv1.z,vv1.w,
                              vv2.x,vv2.y,vv2.z,vv2.w, vv3.x,vv3.y,vv3.z,vv3.w};
        float a0 = 0.f, a1 = 0.f, a2 = 0.f, a3 = 0.f;
        #pragma unroll
        for (int o2 = 0; o2 < OO; ++o2) {
            const float4 wv = wzr[o2];
            a0 += wv.x * vs[o2]; a1 += wv.y * vs[o2];
            a2 += wv.z * vs[o2]; a3 += wv.w * vs[o2];
        }
        *(float4*)(z + (d*MM + mz)*II + ihz*4) =
            make_float4(a0*LOG2E, a1*LOG2E, a2*LOG2E, a3*LOG2E);
    }
    __syncthreads();                                  // BARRIER 2

    // ---- prefetch z2's W o-half NOW (consumed after BARRIER 3; loads
    //      overlap softmax-d compute) ----
    const int mF = lane & 31;                         // m owned in tail
    const int ph = lane >> 5;                         // p-half (0/1)
    float4 w2r[16];
    {
        const float* wz2p = W + ((size_t)(d*MM + mF)*OO) * II + ph*(8*II);
        #pragma unroll
        for (int k = 0; k < 16; ++k)
            w2r[k] = *(const float4*)(wz2p + 4*k);
    }

    // ======== softmax over d: cds[d][m][p] = e_d / sum_d e_d ========
    // (|b| small -> no max subtraction; e computed ONCE, reused by y2)
    // 576 threads own (m,q), process p=q and p=q+18: z rows read once
    // (18-lane same-m groups broadcast), single pass.
    if (tid < MM*PH2) {
        const int m = tid / PH2, q = tid - m*PH2;
        const float* xr = xs + m*XS;
        const float4 xa0 = *(const float4*)(xr + 8*q);
        const float4 xa1 = *(const float4*)(xr + 8*q + 4);
        const float4 xb0 = *(const float4*)(xr + 8*q + 8*PH2);
        const float4 xb1 = *(const float4*)(xr + 8*q + 8*PH2 + 4);
        float eA[DD], eB[DD];
        float seA = 0.f, seB = 0.f;
        #pragma unroll
        for (int d2 = 0; d2 < DD; ++d2) {
            const float4* zp = (const float4*)(z + (d2*MM + m)*II);
            const float4 z0 = zp[0], z1 = zp[1];
            eA[d2] = EXP2(dot8(xa0, xa1, z0, z1)); seA += eA[d2];
            eB[d2] = EXP2(dot8(xb0, xb1, z0, z1)); seB += eB[d2];
        }
        const float rA = RCP(seA);
        const float rB = RCP(seB);
        #pragma unroll
        for (int d2 = 0; d2 < DD; ++d2) {
            float* cp = cds + (d2*MM + m)*RS;
            cp[q]       = eA[d2] * rA;
            cp[q + PH2] = eB[d2] * rB;
        }
    }
    __syncthreads();                                  // BARRIER 3 (last)

    // ======== tail: y2 -> s2(regs) -> v2 -> z2(regs) -> final -> s3(regs) -> out ========
    {
        const float* __restrict__ zd = z + d*(MM*II);
        float* __restrict__ yd = y + d*(MM*II);

        const float* xrow = xs + mF*XS + ph*(8*PH2);  // all reads: base + imm offset
        const float4 zf0 = *(const float4*)(zd + mF*II);       // K*z1 halves
        const float4 zf1 = *(const float4*)(zd + mF*II + 4);

        // ---- y2: 18 iters, precomputed probs from cds (no dot8/exp2) ----
        {
            const float* cp = cds + (d*MM + mF)*RS + ph*PH2;
            float a0=0.f,a1=0.f,a2=0.f,a3=0.f,a4=0.f,a5=0.f,a6=0.f,a7=0.f;
            #pragma unroll 6
            for (int q = 0; q < PH2; ++q) {
                const float4 x0 = *(const float4*)(xrow + 8*q);
                const float4 x1 = *(const float4*)(xrow + 8*q + 4);
                const float e = cp[q];
                a0 += e*x0.x; a1 += e*x0.y; a2 += e*x0.z; a3 += e*x0.w;
                a4 += e*x1.x; a5 += e*x1.y; a6 += e*x1.z; a7 += e*x1.w;
            }
            a0 += __shfl_xor(a0, 32, 64); a1 += __shfl_xor(a1, 32, 64);
            a2 += __shfl_xor(a2, 32, 64); a3 += __shfl_xor(a3, 32, 64);
            a4 += __shfl_xor(a4, 32, 64); a5 += __shfl_xor(a5, 32, 64);
            a6 += __shfl_xor(a6, 32, 64); a7 += __shfl_xor(a7, 32, 64);
            const float4 wv = ph ? make_float4(a4,a5,a6,a7) : make_float4(a0,a1,a2,a3);
            *(float4*)(yd + mF*II + ph*4) = wv;
        }
        // in-wave LDS write->read ordering via lgkmcnt; no barrier

        // ---- s2 (from regs) -> v2 ----
        float s2 = 0.f;
        #pragma unroll
        for (int j = 0; j < 8; ++j) {
            const float4* yp = (const float4*)(yd + (qq*8 + j)*II);
            s2 += dot8(wr0[j], wr1[j], yp[0], yp[1]);
        }
        s2 += __shfl_xor(s2, 16, 64);
        s2 += __shfl_xor(s2, 32, 64);
        float sq = s2 * s2;
        sq += __shfl_xor(sq, 1, 64);
        sq += __shfl_xor(sq, 2, 64);
        sq += __shfl_xor(sq, 4, 64);
        sq += __shfl_xor(sq, 8, 64);
        const float v2 = (sq / (1.f + sq)) * (s2 / sqrtf(sq + 1e-7f));
        if (lane < OO) v_l[d*OO + lane] = v2;
        const float4 vv0 = *(const float4*)(v_l + d*OO);
        const float4 vv1 = *(const float4*)(v_l + d*OO + 4);
        const float4 vv2 = *(const float4*)(v_l + d*OO + 8);
        const float4 vv3 = *(const float4*)(v_l + d*OO + 12);
        // ph-select the o-half this lane needs (static indexing after select;
        // avoids runtime-indexed vs[16] -> scratch, rule #20)
        const float4 svA = ph ? vv2 : vv0;
        const float4 svB = ph ? vv3 : vv1;
        const float vsel[8] = {svA.x,svA.y,svA.z,svA.w, svB.x,svB.y,svB.z,svB.w};

        // ---- z2: lane (mF, ph) does its o-half (prefetched W), xor(32) combine ----
        float4 zf20, zf21;
        {
            float b0=0.f,b1=0.f,b2=0.f,b3=0.f,b4=0.f,b5=0.f,b6=0.f,b7=0.f;
            #pragma unroll
            for (int j = 0; j < 8; ++j) {
                const float4 w0 = w2r[2*j];
                const float4 w1 = w2r[2*j + 1];
                const float sv = vsel[j];
                b0 += w0.x*sv; b1 += w0.y*sv; b2 += w0.z*sv; b3 += w0.w*sv;
                b4 += w1.x*sv; b5 += w1.y*sv; b6 += w1.z*sv; b7 += w1.w*sv;
            }
            b0 += __shfl_xor(b0, 32, 64); b1 += __shfl_xor(b1, 32, 64);
            b2 += __shfl_xor(b2, 32, 64); b3 += __shfl_xor(b3, 32, 64);
            b4 += __shfl_xor(b4, 32, 64); b5 += __shfl_xor(b5, 32, 64);
            b6 += __shfl_xor(b6, 32, 64); b7 += __shfl_xor(b7, 32, 64);
            zf20 = make_float4(zf0.x + b0*LOG2E, zf0.y + b1*LOG2E,
                               zf0.z + b2*LOG2E, zf0.w + b3*LOG2E);
            zf21 = make_float4(zf1.x + b4*LOG2E, zf1.y + b5*LOG2E,
                               zf1.z + b6*LOG2E, zf1.w + b7*LOG2E);
        }

        // ---- final softmax over P: single pass, exp2 ----
        {
            float se = 0.f;
            float a0=0.f,a1=0.f,a2=0.f,a3=0.f,a4=0.f,a5=0.f,a6=0.f,a7=0.f;
            #pragma unroll 6
            for (int q = 0; q < PH2; ++q) {
                const float4 x0 = *(const float4*)(xrow + 8*q);
                const float4 x1 = *(const float4*)(xrow + 8*q + 4);
                const float e = EXP2(dot8(x0, x1, zf20, zf21));
                se += e;
                a0 += e*x0.x; a1 += e*x0.y; a2 += e*x0.z; a3 += e*x0.w;
                a4 += e*x1.x; a5 += e*x1.y; a6 += e*x1.z; a7 += e*x1.w;
            }
            se += __shfl_xor(se, 32, 64);
            a0 += __shfl_xor(a0, 32, 64); a1 += __shfl_xor(a1, 32, 64);
            a2 += __shfl_xor(a2, 32, 64); a3 += __shfl_xor(a3, 32, 64);
            a4 += __shfl_xor(a4, 32, 64); a5 += __shfl_xor(a5, 32, 64);
            a6 += __shfl_xor(a6, 32, 64); a7 += __shfl_xor(a7, 32, 64);
            const float rs = RCP(se);
            const float4 wv = ph ? make_float4(a4*rs,a5*rs,a6*rs,a7*rs)
                                 : make_float4(a0*rs,a1*rs,a2*rs,a3*rs);
            *(float4*)(yd + mF*II + ph*4) = wv;
        }

        // ---- s3 (from regs) -> squash -> out ----
        float s3 = 0.f;
        #pragma unroll
        for (int j = 0; j < 8; ++j) {
            const float4* yp = (const float4*)(yd + (qq*8 + j)*II);
            s3 += dot8(wr0[j], wr1[j], yp[0], yp[1]);
        }
        s3 += __shfl_xor(s3, 16, 64);
        s3 += __shfl_xor(s3, 32, 64);
        float sq3 = s3 * s3;
        sq3 += __shfl_xor(sq3, 1, 64);
        sq3 += __shfl_xor(sq3, 2, 64);
        sq3 += __shfl_xor(sq3, 4, 64);
        sq3 += __shfl_xor(sq3, 8, 64);
        const float r = (sq3 / (1.f + sq3)) * (s3 / sqrtf(sq3 + 1e-7f));
        if (lane < OO)
            out[(size_t)bidx * (DD*OO) + d*OO + o] = r;
    }
}

extern "C" void kernel_launch(void* const* d_in, const int* in_sizes, int n_in,
                              void* d_out, int out_size, void* d_ws, size_t ws_size,
                              hipStream_t stream) {
    (void)in_sizes; (void)n_in; (void)out_size; (void)d_ws; (void)ws_size;
    const float* x = (const float*)d_in[0];  // (B, M, P, I)
    const float* W = (const float*)d_in[1];  // (1, D, M, 1, O, I)
    float* out = (float*)d_out;              // (B, D, O)
    caps_routing<<<dim3(BB), dim3(NT), 0, stream>>>(x, W, out);
}

// Round 7
// 74.600 us; speedup vs baseline: 1.1047x; 1.0879x over previous
//
#include <hip/hip_runtime.h>
#include <math.h>

// CapsShapeLayer: B=256, D=10, M=32, P=36, I=8, O=16, 3 routing iters
// R19 = exact revert to R16 (measured best, 74.71 us).
// Experiment map around this point (all measured, all regressed):
//  - R15: ybar via LDS + extra barrier        -> +0.2 us (barrier cost)
//  - R17: __shfl broadcasts replace v_l LDS   -> +7.7 us (ds_bpermute chains)
//  - R18: W-slice register prefetch           -> +6.4 us (VGPR spill: 10-wave
//         block needs 3 waves/SIMD -> ~168 VGPR cap; +128 live regs spilled)
// R16's content:
//  (1) padded stride XS=292 (no XOR swizzle): tail b128 reads bank-balanced
//      (8 accesses/bank floor), all x LDS accesses base + imm offset.
//  (2) ybar from global, full unroll, on threads 384-639 (light stage waves).
//  (3) softmax-d: 576 threads own (m,q), handle p=q and p=q+18 -> z rows
//      read once, normalized probs cds stored, reused by y2 (no recompute).
//  (4) rcp for softmax denominators (tolerance-safe, ~1e-7 rel err).
// Skeleton: 1 block/batch, 10 waves, wave owns d, 3 barriers.
// Wave caches its W[d] s-slice in 64 VGPRs; log2(e) folded into stored z.
#define BB 256
#define DD 10
#define MM 32
#define PP 36
#define PH2 18
#define II 8
#define OO 16
#define NT 640        // 10 waves = one per d
#define XS 292        // xs row stride (pad 4: 16B-aligned, bank-balanced b128)
#define RS 37         // c row stride: gcd(5,32)=1 -> conflict-free over m
#define LOG2E 1.44269504088896f
#define EXP2(v) __builtin_amdgcn_exp2f(v)
#define RCP(v)  __builtin_amdgcn_rcpf(v)

__device__ __forceinline__ float dot8(const float4 a0, const float4 a1,
                                      const float4 b0, const float4 b1) {
    return a0.x*b0.x + a0.y*b0.y + a0.z*b0.z + a0.w*b0.w
         + a1.x*b1.x + a1.y*b1.y + a1.z*b1.z + a1.w*b1.w;
}

__global__ void __launch_bounds__(NT, 3) caps_routing(
    const float* __restrict__ x,   // (B, M, P, I)
    const float* __restrict__ W,   // (D, M, O, I)
    float* __restrict__ out)       // (B, D, O)
{
    const int bidx = blockIdx.x;
    const int tid  = threadIdx.x;
    const int wave = tid >> 6;          // d owned by this wave (0..9)
    const int lane = tid & 63;
    const float* __restrict__ xb = x + (size_t)bidx * (MM*PP*II);

    __shared__ __align__(16) float xs  [MM*XS];     // 37376 B  x staged once (padded)
    __shared__ __align__(16) float z   [DD*MM*II];  // 10240 B  K*z1 (softmax-d needs all d)
    __shared__ __align__(16) float y   [DD*MM*II];  // 10240 B  per-wave y scratch
    __shared__ __align__(16) float ybar[MM*II];     //  1024 B
    __shared__ __align__(16) float cds [DD*MM*RS];  // 47360 B  normalized c2[d][m][p]
    __shared__ __align__(16) float v_l [DD*OO];     //   640 B
    // total 106880 B (1 block/CU regardless; 160 KiB available)

    const int d  = wave;
    const int o  = lane & 15, qq = lane >> 4;       // s-stage laning: (o, m-quarter)

    // ---- cache this wave's W[d] s-slice in regs: 8 rows (m=qq*8+j) x 32B ----
    float4 wr0[8], wr1[8];
    #pragma unroll
    for (int j = 0; j < 8; ++j) {
        const float4* wp = (const float4*)(W + ((size_t)((d*MM + qq*8 + j)*OO + o)) * II);
        wr0[j] = wp[0]; wr1[j] = wp[1];
    }

    // ======== stage 0: x -> LDS (padded rows) + ybar from global ========
    {
        const float4* xg = (const float4*)xb;
        #pragma unroll
        for (int k = 0; k < 4; ++k) {                 // 2304 float4 over 640 thr
            const int t = tid + k*NT;                 // tid>=384 does only 3 iters
            if (t < MM*72) {
                const int m = t / 72, c = t - m*72;
                *(float4*)(xs + m*XS + 4*c) = xg[t];
            }
        }
        if (tid >= NT - MM*II) {                      // ybar on threads 384..639
            const int m = (tid - (NT - MM*II)) >> 3, i = tid & 7;
            const float* xr = xb + m*(PP*II) + i;
            float a0 = 0.f, a1 = 0.f, a2 = 0.f, a3 = 0.f;
            #pragma unroll
            for (int p = 0; p < PP; p += 4) {         // all 36 loads in flight
                a0 += xr[(p    )*II];
                a1 += xr[(p + 1)*II];
                a2 += xr[(p + 2)*II];
                a3 += xr[(p + 3)*II];
            }
            ybar[m*II + i] = 0.1f * ((a0 + a1) + (a2 + a3));
        }
    }
    __syncthreads();                                  // BARRIER 1

    // ======== per-wave: s1 (regs) -> v1 -> K*z1 -> LDS ========
    {
        float s1 = 0.f;
        #pragma unroll
        for (int j = 0; j < 8; ++j) {
            const float4* yp = (const float4*)(ybar + (qq*8 + j)*II);
            s1 += dot8(wr0[j], wr1[j], yp[0], yp[1]);
        }
        s1 += __shfl_xor(s1, 16, 64);
        s1 += __shfl_xor(s1, 32, 64);
        float sq = s1 * s1;
        sq += __shfl_xor(sq, 1, 64);
        sq += __shfl_xor(sq, 2, 64);
        sq += __shfl_xor(sq, 4, 64);
        sq += __shfl_xor(sq, 8, 64);
        const float v1 = (sq / (1.f + sq)) * (s1 / sqrtf(sq + 1e-7f));
        if (lane < OO) v_l[d*OO + lane] = v1;

        // z1: lane = (m, i-half); W b128 over o; store K*z1 for exp2
        const float4 vv0 = *(const float4*)(v_l + d*OO);
        const float4 vv1 = *(const float4*)(v_l + d*OO + 4);
        const float4 vv2 = *(const float4*)(v_l + d*OO + 8);
        const float4 vv3 = *(const float4*)(v_l + d*OO + 12);
        const float vs[16] = {vv0.x,vv0.y,vv0.z,vv0.w, vv1.x,vv1.y,vv1.z,vv1.w,
                              vv2.x,vv2.y,vv2.z,vv2.w, vv3.x,vv3.y,vv3.z,vv3.w};
        const int mz = lane >> 1, ihz = lane & 1;
        const float* wz = W + ((size_t)(d*MM + mz)*OO) * II + ihz*4;
        float a0 = 0.f, a1 = 0.f, a2 = 0.f, a3 = 0.f;
        #pragma unroll
        for (int o2 = 0; o2 < OO; ++o2) {
            const float4 wv = *(const float4*)(wz + o2*II);
            a0 += wv.x * vs[o2]; a1 += wv.y * vs[o2];
            a2 += wv.z * vs[o2]; a3 += wv.w * vs[o2];
        }
        *(float4*)(z + (d*MM + mz)*II + ihz*4) =
            make_float4(a0*LOG2E, a1*LOG2E, a2*LOG2E, a3*LOG2E);
    }
    __syncthreads();                                  // BARRIER 2

    // ======== softmax over d: cds[d][m][p] = e_d / sum_d e_d ========
    // (|b| small -> no max subtraction; e computed ONCE, reused by y2)
    // 576 threads own (m,q), process p=q and p=q+18: z rows read once
    // (18-lane same-m groups broadcast), single pass.
    if (tid < MM*PH2) {
        const int m = tid / PH2, q = tid - m*PH2;
        const float* xr = xs + m*XS;
        const float4 xa0 = *(const float4*)(xr + 8*q);
        const float4 xa1 = *(const float4*)(xr + 8*q + 4);
        const float4 xb0 = *(const float4*)(xr + 8*q + 8*PH2);
        const float4 xb1 = *(const float4*)(xr + 8*q + 8*PH2 + 4);
        float eA[DD], eB[DD];
        float seA = 0.f, seB = 0.f;
        #pragma unroll
        for (int d2 = 0; d2 < DD; ++d2) {
            const float4* zp = (const float4*)(z + (d2*MM + m)*II);
            const float4 z0 = zp[0], z1 = zp[1];
            eA[d2] = EXP2(dot8(xa0, xa1, z0, z1)); seA += eA[d2];
            eB[d2] = EXP2(dot8(xb0, xb1, z0, z1)); seB += eB[d2];
        }
        const float rA = RCP(seA);
        const float rB = RCP(seB);
        #pragma unroll
        for (int d2 = 0; d2 < DD; ++d2) {
            float* cp = cds + (d2*MM + m)*RS;
            cp[q]       = eA[d2] * rA;
            cp[q + PH2] = eB[d2] * rB;
        }
    }
    __syncthreads();                                  // BARRIER 3 (last)

    // ======== tail: y2 -> s2(regs) -> v2 -> z2(regs) -> final -> s3(regs) -> out ========
    {
        const float* __restrict__ zd = z + d*(MM*II);
        float* __restrict__ yd = y + d*(MM*II);

        const int mF = lane & 31;                     // m owned by this lane
        const int ph = lane >> 5;                     // p-half (0/1), partner = lane^32
        const float* xrow = xs + mF*XS + ph*(8*PH2);  // all reads: base + imm offset
        const float4 zf0 = *(const float4*)(zd + mF*II);       // K*z1 halves
        const float4 zf1 = *(const float4*)(zd + mF*II + 4);

        // ---- y2: 18 iters, precomputed probs from cds (no dot8/exp2) ----
        {
            const float* cp = cds + (d*MM + mF)*RS + ph*PH2;
            float a0=0.f,a1=0.f,a2=0.f,a3=0.f,a4=0.f,a5=0.f,a6=0.f,a7=0.f;
            #pragma unroll 6
            for (int q = 0; q < PH2; ++q) {
                const float4 x0 = *(const float4*)(xrow + 8*q);
                const float4 x1 = *(const float4*)(xrow + 8*q + 4);
                const float e = cp[q];
                a0 += e*x0.x; a1 += e*x0.y; a2 += e*x0.z; a3 += e*x0.w;
                a4 += e*x1.x; a5 += e*x1.y; a6 += e*x1.z; a7 += e*x1.w;
            }
            a0 += __shfl_xor(a0, 32, 64); a1 += __shfl_xor(a1, 32, 64);
            a2 += __shfl_xor(a2, 32, 64); a3 += __shfl_xor(a3, 32, 64);
            a4 += __shfl_xor(a4, 32, 64); a5 += __shfl_xor(a5, 32, 64);
            a6 += __shfl_xor(a6, 32, 64); a7 += __shfl_xor(a7, 32, 64);
            const float4 wv = ph ? make_float4(a4,a5,a6,a7) : make_float4(a0,a1,a2,a3);
            *(float4*)(yd + mF*II + ph*4) = wv;
        }
        // in-wave LDS write->read ordering via lgkmcnt; no barrier

        // ---- s2 (from regs) -> v2 ----
        float s2 = 0.f;
        #pragma unroll
        for (int j = 0; j < 8; ++j) {
            const float4* yp = (const float4*)(yd + (qq*8 + j)*II);
            s2 += dot8(wr0[j], wr1[j], yp[0], yp[1]);
        }
        s2 += __shfl_xor(s2, 16, 64);
        s2 += __shfl_xor(s2, 32, 64);
        float sq = s2 * s2;
        sq += __shfl_xor(sq, 1, 64);
        sq += __shfl_xor(sq, 2, 64);
        sq += __shfl_xor(sq, 4, 64);
        sq += __shfl_xor(sq, 8, 64);
        const float v2 = (sq / (1.f + sq)) * (s2 / sqrtf(sq + 1e-7f));
        if (lane < OO) v_l[d*OO + lane] = v2;
        const float4 vv0 = *(const float4*)(v_l + d*OO);
        const float4 vv1 = *(const float4*)(v_l + d*OO + 4);
        const float4 vv2 = *(const float4*)(v_l + d*OO + 8);
        const float4 vv3 = *(const float4*)(v_l + d*OO + 12);
        // ph-select the o-half this lane needs (static indexing after select;
        // avoids runtime-indexed vs[16] -> scratch, rule #20)
        const float4 svA = ph ? vv2 : vv0;
        const float4 svB = ph ? vv3 : vv1;
        const float vsel[8] = {svA.x,svA.y,svA.z,svA.w, svB.x,svB.y,svB.z,svB.w};

        // ---- z2: lane (mF, ph) does its o-half (global W), xor(32) combine ----
        float4 zf20, zf21;
        {
            const float* wz = W + ((size_t)(d*MM + mF)*OO) * II;
            float b0=0.f,b1=0.f,b2=0.f,b3=0.f,b4=0.f,b5=0.f,b6=0.f,b7=0.f;
            #pragma unroll
            for (int j = 0; j < 8; ++j) {
                const int o2 = ph*8 + j;
                const float4 w0 = *(const float4*)(wz + o2*II);
                const float4 w1 = *(const float4*)(wz + o2*II + 4);
                const float sv = vsel[j];
                b0 += w0.x*sv; b1 += w0.y*sv; b2 += w0.z*sv; b3 += w0.w*sv;
                b4 += w1.x*sv; b5 += w1.y*sv; b6 += w1.z*sv; b7 += w1.w*sv;
            }
            b0 += __shfl_xor(b0, 32, 64); b1 += __shfl_xor(b1, 32, 64);
            b2 += __shfl_xor(b2, 32, 64); b3 += __shfl_xor(b3, 32, 64);
            b4 += __shfl_xor(b4, 32, 64); b5 += __shfl_xor(b5, 32, 64);
            b6 += __shfl_xor(b6, 32, 64); b7 += __shfl_xor(b7, 32, 64);
            zf20 = make_float4(zf0.x + b0*LOG2E, zf0.y + b1*LOG2E,
                               zf0.z + b2*LOG2E, zf0.w + b3*LOG2E);
            zf21 = make_float4(zf1.x + b4*LOG2E, zf1.y + b5*LOG2E,
                               zf1.z + b6*LOG2E, zf1.w + b7*LOG2E);
        }

        // ---- final softmax over P: single pass, exp2 ----
        {
            float se = 0.f;
            float a0=0.f,a1=0.f,a2=0.f,a3=0.f,a4=0.f,a5=0.f,a6=0.f,a7=0.f;
            #pragma unroll 6
            for (int q = 0; q < PH2; ++q) {
                const float4 x0 = *(const float4*)(xrow + 8*q);
                const float4 x1 = *(const float4*)(xrow + 8*q + 4);
                const float e = EXP2(dot8(x0, x1, zf20, zf21));
                se += e;
                a0 += e*x0.x; a1 += e*x0.y; a2 += e*x0.z; a3 += e*x0.w;
                a4 += e*x1.x; a5 += e*x1.y; a6 += e*x1.z; a7 += e*x1.w;
            }
            se += __shfl_xor(se, 32, 64);
            a0 += __shfl_xor(a0, 32, 64); a1 += __shfl_xor(a1, 32, 64);
            a2 += __shfl_xor(a2, 32, 64); a3 += __shfl_xor(a3, 32, 64);
            a4 += __shfl_xor(a4, 32, 64); a5 += __shfl_xor(a5, 32, 64);
            a6 += __shfl_xor(a6, 32, 64); a7 += __shfl_xor(a7, 32, 64);
            const float rs = RCP(se);
            const float4 wv = ph ? make_float4(a4*rs,a5*rs,a6*rs,a7*rs)
                                 : make_float4(a0*rs,a1*rs,a2*rs,a3*rs);
            *(float4*)(yd + mF*II + ph*4) = wv;
        }

        // ---- s3 (from regs) -> squash -> out ----
        float s3 = 0.f;
        #pragma unroll
        for (int j = 0; j < 8; ++j) {
            const float4* yp = (const float4*)(yd + (qq*8 + j)*II);
            s3 += dot8(wr0[j], wr1[j], yp[0], yp[1]);
        }
        s3 += __shfl_xor(s3, 16, 64);
        s3 += __shfl_xor(s3, 32, 64);
        float sq3 = s3 * s3;
        sq3 += __shfl_xor(sq3, 1, 64);
        sq3 += __shfl_xor(sq3, 2, 64);
        sq3 += __shfl_xor(sq3, 4, 64);
        sq3 += __shfl_xor(sq3, 8, 64);
        const float r = (sq3 / (1.f + sq3)) * (s3 / sqrtf(sq3 + 1e-7f));
        if (lane < OO)
            out[(size_t)bidx * (DD*OO) + d*OO + o] = r;
    }
}

extern "C" void kernel_launch(void* const* d_in, const int* in_sizes, int n_in,
                              void* d_out, int out_size, void* d_ws, size_t ws_size,
                              hipStream_t stream) {
    (void)in_sizes; (void)n_in; (void)out_size; (void)d_ws; (void)ws_size;
    const float* x = (const float*)d_in[0];  // (B, M, P, I)
    const float* W = (const float*)d_in[1];  // (1, D, M, 1, O, I)
    float* out = (float*)d_out;              // (B, D, O)
    caps_routing<<<dim3(BB), dim3(NT), 0, stream>>>(x, W, out);
}